// Round 8
// baseline (250.311 us; speedup 1.0000x reference)
//
#include <hip/hip_runtime.h>

#define BATCH 32
#define HH 1024
#define WW 1024
#define NPIX (HH * WW)
#define NEROS 10
#define TPS 64                // 16-row tiles per sample (tail kernel)
#define NTILES (BATCH * TPS)  // 2048 (tail grid)
#define FWPS 32               // flag words per sample: uint per 32 rows
#define NB0 (BATCH * 128)     // conv0: 4096 blocks, each 8 rows x 1024 px

__device__ __forceinline__ float4 ld4f(const float* p) {
    return *reinterpret_cast<const float4*>(p);
}

// ---------------- iteration 0: barrier-free streaming bound+conv ----------------
// Block = 8 rows x 1024 px, 4 waves; wave w owns the 8-row x 256-px patch at
// px [256w, 256w+256). Each wave burst-issues ALL 20 input loads (10 rows x
// {pred,tgt}) -> ~20KB in flight, computes bound in regs as loads drain,
// stencils 8 rows from registers. No LDS staging, no barrier-coupled load
// phases; only a 256B seam exchange + final reduce. Rows written
// unconditionally (flags still track nonzero rows exactly for the tail).
__global__ __launch_bounds__(256, 4) void conv0_kernel(
    const float* __restrict__ pred, const float* __restrict__ tgt,
    float* __restrict__ out, unsigned* __restrict__ Fout,
    unsigned* __restrict__ cntOut, unsigned* __restrict__ omin,
    unsigned* __restrict__ omax, double* __restrict__ osum) {
    int blk = blockIdx.x;
    blk = (blk & 7) * (NB0 >> 3) + (blk >> 3);  // XCD swizzle (4096%8==0)
    const int s = blk >> 7, g = blk & 127;      // g: 8-row group
    const int y0 = g << 3;
    const int tid = threadIdx.x, lane = tid & 63, w = tid >> 6;  // w: 0..3
    const size_t sbase = (size_t)s * NPIX;
    const int xb = (w << 8) + (lane << 2);

    __shared__ float seamL[4][8], seamR[4][8];
    __shared__ float smn[4], smx[4], ssm[4];

    // ---- burst: issue all 20 loads for rows [y0-1, y0+9) ----
    float4 pv[10], tv[10];
#pragma unroll
    for (int i = 0; i < 10; ++i) {
        const int y = y0 - 1 + i;
        if (y >= 0 && y < HH) {
            const size_t idx = sbase + (size_t)y * WW + xb;
            pv[i] = ld4f(pred + idx);
            tv[i] = ld4f(tgt + idx);
        } else {
            pv[i] = make_float4(0.f, 0.f, 0.f, 0.f);
            tv[i] = make_float4(0.f, 0.f, 0.f, 0.f);
        }
    }

    // ---- bound rows in registers (loads drain progressively) ----
    float b[10][4];
#pragma unroll
    for (int i = 0; i < 10; ++i) {
        b[i][0] = (pv[i].x - tv[i].x) * (pv[i].x - tv[i].x);
        b[i][1] = (pv[i].y - tv[i].y) * (pv[i].y - tv[i].y);
        b[i][2] = (pv[i].z - tv[i].z) * (pv[i].z - tv[i].z);
        b[i][3] = (pv[i].w - tv[i].w) * (pv[i].w - tv[i].w);
    }

    // ---- seam exchange: center rows' edge values across wave boundaries ----
    if (lane == 0) {
#pragma unroll
        for (int r = 1; r <= 8; ++r) seamL[w][r - 1] = b[r][0];
    }
    if (lane == 63) {
#pragma unroll
        for (int r = 1; r <= 8; ++r) seamR[w][r - 1] = b[r][3];
    }
    __syncthreads();

    // ---- stencil 8 rows from registers ----
    float lmin = 3.4e38f, lmax = 0.f, lsum = 0.f;
    unsigned rowbits = 0u;
#pragma unroll
    for (int r = 1; r <= 8; ++r) {
        const int y = y0 + r - 1;
        float lf0 = __shfl_up(b[r][3], 1);
        if (lane == 0) lf0 = (w > 0) ? seamR[w - 1][r - 1] : 0.f;
        float rt3 = __shfl_down(b[r][0], 1);
        if (lane == 63) rt3 = (w < 3) ? seamL[w + 1][r - 1] : 0.f;
        const float lv[4] = {lf0, b[r][0], b[r][1], b[r][2]};
        const float rv[4] = {b[r][1], b[r][2], b[r][3], rt3};
        float O[4];
        bool nz = false;
#pragma unroll
        for (int j = 0; j < 4; ++j) {
            const float conv =
                0.2f * (b[r - 1][j] + b[r + 1][j] + b[r][j] + lv[j] + rv[j]);
            const float er = fmaxf(conv - 0.5f, 0.f);
            O[j] = er;
            lmin = fminf(lmin, er);
            lmax = fmaxf(lmax, er);
            lsum += er;
            nz = nz || (er > 0.f);
        }
        // unconditional write: memory always holds real values (zeros incl.)
        *reinterpret_cast<float4*>(out + sbase + (size_t)y * WW + xb) =
            make_float4(O[0], O[1], O[2], O[3]);
        if (__ballot(nz) != 0ull) rowbits |= 1u << (r - 1);
    }

    // flags: one atomicOr per wave (bit = row has nonzero anywhere)
    if (lane == 0 && rowbits) {
        atomicOr(&Fout[s * FWPS + (g >> 2)], rowbits << ((g & 3) * 8));
        atomicAdd(cntOut, 1u);
    }

    // ---- reduce ----
#pragma unroll
    for (int off = 32; off > 0; off >>= 1) {
        lmin = fminf(lmin, __shfl_down(lmin, off));
        lmax = fmaxf(lmax, __shfl_down(lmax, off));
        lsum += __shfl_down(lsum, off);
    }
    if (lane == 0) {
        smn[w] = lmin;
        smx[w] = lmax;
        ssm[w] = lsum;
    }
    __syncthreads();
    if (tid == 0) {
        float bmn = smn[0], bmx = smx[0], bsm = ssm[0];
#pragma unroll
        for (int i = 1; i < 4; ++i) {
            bmn = fminf(bmn, smn[i]);
            bmx = fmaxf(bmx, smx[i]);
            bsm += ssm[i];
        }
        atomicMin(&omin[s], __float_as_uint(bmn));
        if (bmx > 0.f) atomicMax(&omax[s], __float_as_uint(bmx));
        if (bsm > 0.f) atomicAdd(&osum[s], (double)bsm);
    }
}

// ---------------- iterations 1..9 (sparse tail) ----------------
// Block = 16-row tile, 4 waves; wave w owns rows [ry+4w, ry+4w+4); lane owns
// 16 px. Flag bit per row (uint per 32 rows): set = row has a nonzero.
// Unflagged rows are exact zeros and their memory is never read.
__global__ __launch_bounds__(256, 4) void convt_kernel(
    const float* __restrict__ in, float* __restrict__ out,
    const unsigned* __restrict__ Fprev, unsigned* __restrict__ Fout,
    const unsigned* __restrict__ cntPrev, unsigned* __restrict__ cntOut,
    const unsigned* __restrict__ pmin, const unsigned* __restrict__ pmax,
    unsigned* __restrict__ omin, unsigned* __restrict__ omax,
    double* __restrict__ osum) {
    if (*cntPrev == 0u) return;  // field died: absorbing state

    int blk = blockIdx.x;
    blk = (blk & 7) * (NTILES >> 3) + (blk >> 3);
    const int s = blk >> 6, ty = blk & 63, ry = ty << 4;
    const int tid = threadIdx.x, lane = tid & 63, w = tid >> 6;
    const int xb = lane << 4;
    const size_t sbase = (size_t)s * NPIX;

    // M: bit (i+1) = row ry+i flagged, i in [-1,16]
    const unsigned* Fs = Fprev + s * FWPS;
    const int w32 = ty >> 1, sh = (ty & 1) * 16;
    const unsigned cur = Fs[w32];
    unsigned M = ((cur >> sh) & 0xFFFFu) << 1;
    if (ty > 0)
        M |= (ty & 1) ? ((cur >> 15) & 1u) : ((Fs[w32 - 1] >> 31) & 1u);
    if (ty < TPS - 1) {
        const unsigned nb = (ty & 1) ? (Fs[w32 + 1] & 1u) : ((cur >> 16) & 1u);
        M |= nb << 17;
    }
    if (M == 0u) {  // nothing in reach: tile output exactly zero
        if (tid == 0) atomicMin(&omin[s], 0u);
        return;
    }

    float a = 1.f, cc = 0.f;
    {
        const float mn = __uint_as_float(pmin[s]);
        const float mx = __uint_as_float(pmax[s]);
        const float ptp = mx - mn;
        if (ptp > 0.f) { a = 1.f / ptp; cc = mn; }
    }

    const int r0 = w << 2;
    float A[16], B[16], C[16], O[16];

    auto loadRow = [&](int y, float* V) {
        const bool ok =
            (y >= 0 && y < HH) && (((M >> (y - ry + 1)) & 1u) != 0u);
        if (!ok) {
#pragma unroll
            for (int j = 0; j < 16; ++j) V[j] = 0.f;
            return;
        }
        const size_t idx = sbase + (size_t)y * WW + xb;
#pragma unroll
        for (int q = 0; q < 4; ++q) {
            const float4 v = ld4f(in + idx + 4 * q);
            V[4 * q + 0] = v.x;
            V[4 * q + 1] = v.y;
            V[4 * q + 2] = v.z;
            V[4 * q + 3] = v.w;
        }
    };

    loadRow(ry + r0 - 1, A);
    loadRow(ry + r0, B);

    float lmin = 3.4e38f, lmax = 0.f, lsum = 0.f;
    unsigned rowbits = 0u;

#pragma unroll
    for (int r = 0; r < 4; ++r) {
        const int y = ry + r0 + r;
        loadRow(y + 1, C);
        const bool act = (((M >> (r0 + r)) & 7u) != 0u);
        if (act) {
            float lfe = __shfl_up(B[15], 1);
            if (lane == 0) lfe = 0.f;
            float rte = __shfl_down(B[0], 1);
            if (lane == 63) rte = 0.f;
            const float vert =
                1.f + (y > 0 ? 1.f : 0.f) + (y < HH - 1 ? 1.f : 0.f);
            bool nz = false;
#pragma unroll
            for (int j = 0; j < 16; ++j) {
                const float lf = (j == 0) ? lfe : B[j - 1];
                const float rt = (j == 15) ? rte : B[j + 1];
                const float conv = 0.2f * (A[j] + C[j] + B[j] + lf + rt);
                const int x = xb + j;
                const float kf = 0.2f * (vert + (x > 0 ? 1.f : 0.f) +
                                         (x < WW - 1 ? 1.f : 0.f));
                const float dil = (conv - cc * kf) * a;
                const float er = fmaxf(dil - 0.5f, 0.f);
                O[j] = er;
                lmin = fminf(lmin, er);
                lmax = fmaxf(lmax, er);
                lsum += er;
                nz = nz || (er > 0.f);
            }
            if (__ballot(nz) != 0ull) {
                const size_t oidx = sbase + (size_t)y * WW + xb;
#pragma unroll
                for (int q = 0; q < 4; ++q)
                    *reinterpret_cast<float4*>(out + oidx + 4 * q) =
                        make_float4(O[4 * q], O[4 * q + 1], O[4 * q + 2],
                                    O[4 * q + 3]);
                rowbits |= 1u << (r0 + r);
            }
        } else {
            lmin = fminf(lmin, 0.f);
        }
#pragma unroll
        for (int j = 0; j < 16; ++j) {
            A[j] = B[j];
            B[j] = C[j];
        }
    }

#pragma unroll
    for (int off = 32; off > 0; off >>= 1) {
        lmin = fminf(lmin, __shfl_down(lmin, off));
        lmax = fmaxf(lmax, __shfl_down(lmax, off));
        lsum += __shfl_down(lsum, off);
    }
    __shared__ float smn[4], smx[4], ssm[4];
    __shared__ unsigned sfb[4];
    if (lane == 0) {
        smn[w] = lmin;
        smx[w] = lmax;
        ssm[w] = lsum;
        sfb[w] = rowbits;
    }
    __syncthreads();
    if (tid == 0) {
        const unsigned fmask = sfb[0] | sfb[1] | sfb[2] | sfb[3];
        float bmn = smn[0], bmx = smx[0], bsm = ssm[0];
#pragma unroll
        for (int i = 1; i < 4; ++i) {
            bmn = fminf(bmn, smn[i]);
            bmx = fmaxf(bmx, smx[i]);
            bsm += ssm[i];
        }
        if (fmask) {
            atomicOr(&Fout[s * FWPS + w32], fmask << sh);
            atomicAdd(cntOut, 1u);
        }
        atomicMin(&omin[s], __float_as_uint(bmn));
        if (bmx > 0.f) atomicMax(&omax[s], __float_as_uint(bmx));
        if (bsm > 0.f) atomicAdd(&osum[s], (double)bsm);
    }
}

__global__ void init_kernel(unsigned* __restrict__ minb,
                            unsigned* __restrict__ maxb,
                            double* __restrict__ sums,
                            unsigned* __restrict__ F,
                            unsigned* __restrict__ cnt) {
    const int i = blockIdx.x * blockDim.x + threadIdx.x;
    if (i < NEROS * BATCH) {
        minb[i] = 0x7f800000u;  // +inf
        maxb[i] = 0u;
        sums[i] = 0.0;
    }
    if (i < NEROS * BATCH * FWPS) F[i] = 0u;
    if (i < NEROS) cnt[i] = 0u;
}

__global__ void final_kernel(const unsigned* __restrict__ minb,
                             const unsigned* __restrict__ maxb,
                             const double* __restrict__ sums,
                             float* __restrict__ out) {
    const int s = threadIdx.x;
    double tot = 0.0;
    if (s < BATCH) {
        for (int k = 0; k < NEROS; ++k) {
            const float mn = __uint_as_float(minb[k * BATCH + s]);
            const float mx = __uint_as_float(maxb[k * BATCH + s]);
            const double sm = sums[k * BATCH + s];
            const float ptp = mx - mn;
            double v;
            if (ptp > 0.f)
                v = (sm - (double)NPIX * (double)mn) / (double)ptp;
            else
                v = sm;
            tot += (double)((k + 1) * (k + 1)) * v;
        }
    }
#pragma unroll
    for (int off = 32; off > 0; off >>= 1) tot += __shfl_down(tot, off);
    if (s == 0) out[0] = (float)(tot / ((double)BATCH * (double)NPIX));
}

extern "C" void kernel_launch(void* const* d_in, const int* in_sizes, int n_in,
                              void* d_out, int out_size, void* d_ws,
                              size_t ws_size, hipStream_t stream) {
    const float* pred = (const float*)d_in[0];
    const float* tgt = (const float*)d_in[1];
    float* out = (float*)d_out;

    float* buf0 = (float*)d_ws;
    float* buf1 = buf0 + (size_t)BATCH * NPIX;
    unsigned* minb = (unsigned*)(buf1 + (size_t)BATCH * NPIX);
    unsigned* maxb = minb + NEROS * BATCH;
    double* sums = (double*)(maxb + NEROS * BATCH);
    unsigned* F = (unsigned*)(sums + NEROS * BATCH);
    unsigned* cnt = F + (size_t)NEROS * BATCH * FWPS;

    init_kernel<<<40, 256, 0, stream>>>(minb, maxb, sums, F, cnt);

    conv0_kernel<<<NB0, 256, 0, stream>>>(pred, tgt, buf0, F, &cnt[0], minb,
                                          maxb, sums);

    float* bufs[2] = {buf0, buf1};
    for (int k = 1; k < NEROS; ++k) {
        const float* src = bufs[(k - 1) & 1];
        float* dst = bufs[k & 1];
        convt_kernel<<<NTILES, 256, 0, stream>>>(
            src, dst, F + (size_t)(k - 1) * BATCH * FWPS,
            F + (size_t)k * BATCH * FWPS, &cnt[k - 1], &cnt[k],
            minb + (size_t)(k - 1) * BATCH, maxb + (size_t)(k - 1) * BATCH,
            minb + (size_t)k * BATCH, maxb + (size_t)k * BATCH,
            sums + (size_t)k * BATCH);
    }

    final_kernel<<<1, 64, 0, stream>>>(minb, maxb, sums, out);
}

// Round 9
// 247.549 us; speedup vs baseline: 1.0112x; 1.0112x over previous
//
#include <hip/hip_runtime.h>

#define BATCH 32
#define HH 1024
#define WW 1024
#define NPIX (HH * WW)
#define NEROS 10
#define TPS 64                // 16-row tiles per sample (tail kernel)
#define NTILES (BATCH * TPS)  // 2048 (tail grid)
#define FWPS 32               // flag words per sample: uint per 32 rows
#define NB0 (BATCH * 512)     // conv0: 16384 blocks, each 2 rows x 1024 px

__device__ __forceinline__ float4 ld4f(const float* p) {
    return *reinterpret_cast<const float4*>(p);
}

// ---------------- iteration 0: R2-regime streaming bound+conv ----------------
// Block = 2 rows x 1024 px, 256 threads; thread owns a 4-px column, loads
// rows [y0-1, y0+3) of pred+tgt (8 independent dwordx4, ~32 VGPRs), computes
// bound in regs, stencils 2 rows (vertical taps in-thread, horizontal via
// shfl; lane 0/63 seam values via 2 scalar loads). No LDS staging, no barrier
// before stores. Unconditional row writes; exact per-row nonzero flags for
// the sparse tail. 32 waves/CU (VGPR<=64), 16384 independent blocks.
__global__ __launch_bounds__(256, 8) void conv0_kernel(
    const float* __restrict__ pred, const float* __restrict__ tgt,
    float* __restrict__ out, unsigned* __restrict__ Fout,
    unsigned* __restrict__ cntOut, unsigned* __restrict__ omin,
    unsigned* __restrict__ omax, double* __restrict__ osum) {
    int blk = blockIdx.x;
    blk = (blk & 7) * (NB0 >> 3) + (blk >> 3);  // XCD swizzle (16384%8==0)
    const int s = blk >> 9, rp = blk & 511;
    const int y0 = rp << 1;  // first of the 2 output rows
    const int tid = threadIdx.x, lane = tid & 63, w = tid >> 6;
    const int x0 = tid << 2;
    const size_t sbase = (size_t)s * NPIX;

    // ---- burst: 8 independent quad loads, rows [y0-1, y0+3) ----
    float4 pv[4], tv[4];
#pragma unroll
    for (int i = 0; i < 4; ++i) {
        const int y = y0 - 1 + i;
        if (y >= 0 && y < HH) {
            const size_t idx = sbase + (size_t)y * WW + x0;
            pv[i] = ld4f(pred + idx);
            tv[i] = ld4f(tgt + idx);
        } else {
            pv[i] = make_float4(0.f, 0.f, 0.f, 0.f);
            tv[i] = make_float4(0.f, 0.f, 0.f, 0.f);
        }
    }
    // seam scalars (wave-boundary lanes only; L1-resident neighbor data)
    float eL[2] = {0.f, 0.f}, eR[2] = {0.f, 0.f};
    if (lane == 0 && x0 > 0) {
#pragma unroll
        for (int r = 0; r < 2; ++r) {
            const size_t idx = sbase + (size_t)(y0 + r) * WW + x0 - 1;
            const float d = pred[idx] - tgt[idx];
            eL[r] = d * d;
        }
    }
    if (lane == 63 && x0 + 4 < WW) {
#pragma unroll
        for (int r = 0; r < 2; ++r) {
            const size_t idx = sbase + (size_t)(y0 + r) * WW + x0 + 4;
            const float d = pred[idx] - tgt[idx];
            eR[r] = d * d;
        }
    }

    // ---- bound rows in registers ----
    float b[4][4];
#pragma unroll
    for (int i = 0; i < 4; ++i) {
        b[i][0] = (pv[i].x - tv[i].x) * (pv[i].x - tv[i].x);
        b[i][1] = (pv[i].y - tv[i].y) * (pv[i].y - tv[i].y);
        b[i][2] = (pv[i].z - tv[i].z) * (pv[i].z - tv[i].z);
        b[i][3] = (pv[i].w - tv[i].w) * (pv[i].w - tv[i].w);
    }

    // ---- stencil 2 rows ----
    float lmin = 3.4e38f, lmax = 0.f, lsum = 0.f;
    unsigned rowbits = 0u;
#pragma unroll
    for (int r = 1; r <= 2; ++r) {
        const int y = y0 + r - 1;
        float lf = __shfl_up(b[r][3], 1);
        if (lane == 0) lf = eL[r - 1];
        float rt = __shfl_down(b[r][0], 1);
        if (lane == 63) rt = eR[r - 1];
        const float lv[4] = {lf, b[r][0], b[r][1], b[r][2]};
        const float rv[4] = {b[r][1], b[r][2], b[r][3], rt};
        float O[4];
        bool nz = false;
#pragma unroll
        for (int j = 0; j < 4; ++j) {
            const float conv =
                0.2f * (b[r - 1][j] + b[r + 1][j] + b[r][j] + lv[j] + rv[j]);
            const float er = fmaxf(conv - 0.5f, 0.f);
            O[j] = er;
            lmin = fminf(lmin, er);
            lmax = fmaxf(lmax, er);
            lsum += er;
            nz = nz || (er > 0.f);
        }
        *reinterpret_cast<float4*>(out + sbase + (size_t)y * WW + x0) =
            make_float4(O[0], O[1], O[2], O[3]);
        if (__ballot(nz) != 0ull) rowbits |= 1u << (r - 1);
    }

    // ---- block reduce (after stores issued) ----
#pragma unroll
    for (int off = 32; off > 0; off >>= 1) {
        lmin = fminf(lmin, __shfl_down(lmin, off));
        lmax = fmaxf(lmax, __shfl_down(lmax, off));
        lsum += __shfl_down(lsum, off);
    }
    __shared__ float smn[4], smx[4], ssm[4];
    __shared__ unsigned sfb[4];
    if (lane == 0) {
        smn[w] = lmin;
        smx[w] = lmax;
        ssm[w] = lsum;
        sfb[w] = rowbits;
    }
    __syncthreads();
    if (tid == 0) {
        const unsigned fmask = sfb[0] | sfb[1] | sfb[2] | sfb[3];
        float bmn = smn[0], bmx = smx[0], bsm = ssm[0];
#pragma unroll
        for (int i = 1; i < 4; ++i) {
            bmn = fminf(bmn, smn[i]);
            bmx = fmaxf(bmx, smx[i]);
            bsm += ssm[i];
        }
        if (fmask) {
            atomicOr(&Fout[s * FWPS + (y0 >> 5)], fmask << (y0 & 31));
            atomicAdd(cntOut, 1u);
        }
        atomicMin(&omin[s], __float_as_uint(bmn));
        if (bmx > 0.f) atomicMax(&omax[s], __float_as_uint(bmx));
        if (bsm > 0.f) atomicAdd(&osum[s], (double)bsm);
    }
}

// ---------------- iterations 1..9 (sparse tail) ----------------
// Block = 16-row tile, 4 waves; wave w owns rows [ry+4w, ry+4w+4); lane owns
// 16 px. Flag bit per row (uint per 32 rows): set = row has a nonzero.
// Unflagged rows are exact zeros and their memory is never read.
__global__ __launch_bounds__(256, 4) void convt_kernel(
    const float* __restrict__ in, float* __restrict__ out,
    const unsigned* __restrict__ Fprev, unsigned* __restrict__ Fout,
    const unsigned* __restrict__ cntPrev, unsigned* __restrict__ cntOut,
    const unsigned* __restrict__ pmin, const unsigned* __restrict__ pmax,
    unsigned* __restrict__ omin, unsigned* __restrict__ omax,
    double* __restrict__ osum) {
    if (*cntPrev == 0u) return;  // field died: absorbing state

    int blk = blockIdx.x;
    blk = (blk & 7) * (NTILES >> 3) + (blk >> 3);
    const int s = blk >> 6, ty = blk & 63, ry = ty << 4;
    const int tid = threadIdx.x, lane = tid & 63, w = tid >> 6;
    const int xb = lane << 4;
    const size_t sbase = (size_t)s * NPIX;

    // M: bit (i+1) = row ry+i flagged, i in [-1,16]
    const unsigned* Fs = Fprev + s * FWPS;
    const int w32 = ty >> 1, sh = (ty & 1) * 16;
    const unsigned cur = Fs[w32];
    unsigned M = ((cur >> sh) & 0xFFFFu) << 1;
    if (ty > 0)
        M |= (ty & 1) ? ((cur >> 15) & 1u) : ((Fs[w32 - 1] >> 31) & 1u);
    if (ty < TPS - 1) {
        const unsigned nb = (ty & 1) ? (Fs[w32 + 1] & 1u) : ((cur >> 16) & 1u);
        M |= nb << 17;
    }
    if (M == 0u) {  // nothing in reach: tile output exactly zero
        if (tid == 0) atomicMin(&omin[s], 0u);
        return;
    }

    float a = 1.f, cc = 0.f;
    {
        const float mn = __uint_as_float(pmin[s]);
        const float mx = __uint_as_float(pmax[s]);
        const float ptp = mx - mn;
        if (ptp > 0.f) { a = 1.f / ptp; cc = mn; }
    }

    const int r0 = w << 2;
    float A[16], B[16], C[16], O[16];

    auto loadRow = [&](int y, float* V) {
        const bool ok =
            (y >= 0 && y < HH) && (((M >> (y - ry + 1)) & 1u) != 0u);
        if (!ok) {
#pragma unroll
            for (int j = 0; j < 16; ++j) V[j] = 0.f;
            return;
        }
        const size_t idx = sbase + (size_t)y * WW + xb;
#pragma unroll
        for (int q = 0; q < 4; ++q) {
            const float4 v = ld4f(in + idx + 4 * q);
            V[4 * q + 0] = v.x;
            V[4 * q + 1] = v.y;
            V[4 * q + 2] = v.z;
            V[4 * q + 3] = v.w;
        }
    };

    loadRow(ry + r0 - 1, A);
    loadRow(ry + r0, B);

    float lmin = 3.4e38f, lmax = 0.f, lsum = 0.f;
    unsigned rowbits = 0u;

#pragma unroll
    for (int r = 0; r < 4; ++r) {
        const int y = ry + r0 + r;
        loadRow(y + 1, C);
        const bool act = (((M >> (r0 + r)) & 7u) != 0u);
        if (act) {
            float lfe = __shfl_up(B[15], 1);
            if (lane == 0) lfe = 0.f;
            float rte = __shfl_down(B[0], 1);
            if (lane == 63) rte = 0.f;
            const float vert =
                1.f + (y > 0 ? 1.f : 0.f) + (y < HH - 1 ? 1.f : 0.f);
            bool nz = false;
#pragma unroll
            for (int j = 0; j < 16; ++j) {
                const float lf = (j == 0) ? lfe : B[j - 1];
                const float rt = (j == 15) ? rte : B[j + 1];
                const float conv = 0.2f * (A[j] + C[j] + B[j] + lf + rt);
                const int x = xb + j;
                const float kf = 0.2f * (vert + (x > 0 ? 1.f : 0.f) +
                                         (x < WW - 1 ? 1.f : 0.f));
                const float dil = (conv - cc * kf) * a;
                const float er = fmaxf(dil - 0.5f, 0.f);
                O[j] = er;
                lmin = fminf(lmin, er);
                lmax = fmaxf(lmax, er);
                lsum += er;
                nz = nz || (er > 0.f);
            }
            if (__ballot(nz) != 0ull) {
                const size_t oidx = sbase + (size_t)y * WW + xb;
#pragma unroll
                for (int q = 0; q < 4; ++q)
                    *reinterpret_cast<float4*>(out + oidx + 4 * q) =
                        make_float4(O[4 * q], O[4 * q + 1], O[4 * q + 2],
                                    O[4 * q + 3]);
                rowbits |= 1u << (r0 + r);
            }
        } else {
            lmin = fminf(lmin, 0.f);
        }
#pragma unroll
        for (int j = 0; j < 16; ++j) {
            A[j] = B[j];
            B[j] = C[j];
        }
    }

#pragma unroll
    for (int off = 32; off > 0; off >>= 1) {
        lmin = fminf(lmin, __shfl_down(lmin, off));
        lmax = fmaxf(lmax, __shfl_down(lmax, off));
        lsum += __shfl_down(lsum, off);
    }
    __shared__ float smn[4], smx[4], ssm[4];
    __shared__ unsigned sfb[4];
    if (lane == 0) {
        smn[w] = lmin;
        smx[w] = lmax;
        ssm[w] = lsum;
        sfb[w] = rowbits;
    }
    __syncthreads();
    if (tid == 0) {
        const unsigned fmask = sfb[0] | sfb[1] | sfb[2] | sfb[3];
        float bmn = smn[0], bmx = smx[0], bsm = ssm[0];
#pragma unroll
        for (int i = 1; i < 4; ++i) {
            bmn = fminf(bmn, smn[i]);
            bmx = fmaxf(bmx, smx[i]);
            bsm += ssm[i];
        }
        if (fmask) {
            atomicOr(&Fout[s * FWPS + w32], fmask << sh);
            atomicAdd(cntOut, 1u);
        }
        atomicMin(&omin[s], __float_as_uint(bmn));
        if (bmx > 0.f) atomicMax(&omax[s], __float_as_uint(bmx));
        if (bsm > 0.f) atomicAdd(&osum[s], (double)bsm);
    }
}

__global__ void init_kernel(unsigned* __restrict__ minb,
                            unsigned* __restrict__ maxb,
                            double* __restrict__ sums,
                            unsigned* __restrict__ F,
                            unsigned* __restrict__ cnt) {
    const int i = blockIdx.x * blockDim.x + threadIdx.x;
    if (i < NEROS * BATCH) {
        minb[i] = 0x7f800000u;  // +inf
        maxb[i] = 0u;
        sums[i] = 0.0;
    }
    if (i < NEROS * BATCH * FWPS) F[i] = 0u;
    if (i < NEROS) cnt[i] = 0u;
}

__global__ void final_kernel(const unsigned* __restrict__ minb,
                             const unsigned* __restrict__ maxb,
                             const double* __restrict__ sums,
                             float* __restrict__ out) {
    const int s = threadIdx.x;
    double tot = 0.0;
    if (s < BATCH) {
        for (int k = 0; k < NEROS; ++k) {
            const float mn = __uint_as_float(minb[k * BATCH + s]);
            const float mx = __uint_as_float(maxb[k * BATCH + s]);
            const double sm = sums[k * BATCH + s];
            const float ptp = mx - mn;
            double v;
            if (ptp > 0.f)
                v = (sm - (double)NPIX * (double)mn) / (double)ptp;
            else
                v = sm;
            tot += (double)((k + 1) * (k + 1)) * v;
        }
    }
#pragma unroll
    for (int off = 32; off > 0; off >>= 1) tot += __shfl_down(tot, off);
    if (s == 0) out[0] = (float)(tot / ((double)BATCH * (double)NPIX));
}

extern "C" void kernel_launch(void* const* d_in, const int* in_sizes, int n_in,
                              void* d_out, int out_size, void* d_ws,
                              size_t ws_size, hipStream_t stream) {
    const float* pred = (const float*)d_in[0];
    const float* tgt = (const float*)d_in[1];
    float* out = (float*)d_out;

    float* buf0 = (float*)d_ws;
    float* buf1 = buf0 + (size_t)BATCH * NPIX;
    unsigned* minb = (unsigned*)(buf1 + (size_t)BATCH * NPIX);
    unsigned* maxb = minb + NEROS * BATCH;
    double* sums = (double*)(maxb + NEROS * BATCH);
    unsigned* F = (unsigned*)(sums + NEROS * BATCH);
    unsigned* cnt = F + (size_t)NEROS * BATCH * FWPS;

    init_kernel<<<40, 256, 0, stream>>>(minb, maxb, sums, F, cnt);

    conv0_kernel<<<NB0, 256, 0, stream>>>(pred, tgt, buf0, F, &cnt[0], minb,
                                          maxb, sums);

    float* bufs[2] = {buf0, buf1};
    for (int k = 1; k < NEROS; ++k) {
        const float* src = bufs[(k - 1) & 1];
        float* dst = bufs[k & 1];
        convt_kernel<<<NTILES, 256, 0, stream>>>(
            src, dst, F + (size_t)(k - 1) * BATCH * FWPS,
            F + (size_t)k * BATCH * FWPS, &cnt[k - 1], &cnt[k],
            minb + (size_t)(k - 1) * BATCH, maxb + (size_t)(k - 1) * BATCH,
            minb + (size_t)k * BATCH, maxb + (size_t)k * BATCH,
            sums + (size_t)k * BATCH);
    }

    final_kernel<<<1, 64, 0, stream>>>(minb, maxb, sums, out);
}

// Round 10
// 122.455 us; speedup vs baseline: 2.0441x; 2.0215x over previous
//
#include <hip/hip_runtime.h>

#define BATCH 32
#define HH 1024
#define WW 1024
#define NPIX (HH * WW)
#define NEROS 10
#define TPS 64                // 16-row tiles per sample (tail kernel)
#define NTILES (BATCH * TPS)  // 2048 (tail grid)
#define NB0 (BATCH * 128)     // conv0: 4096 8-row tiles
#define FRPS 1024             // flag words per sample: ushort chunk-mask per row

__device__ __forceinline__ float4 ld4f(const float* p) {
    return *reinterpret_cast<const float4*>(p);
}

// Flags: per row, a 16-bit mask; bit c set = 64-px chunk c of that row has a
// nonzero. Unflagged chunks are exact zeros and their memory is NEVER read or
// written. Masks are pre-zeroed each launch; writers own their rows.

// ---------------- iteration 0: LDS-staged bound+conv, chunk-sparse writes ----
// Block = 8-row tile, 512 threads (8 waves), 40 KB LDS (4 blocks/CU). Stage
// rows [ry-1, ry+9) of bound=(pred-tgt)^2 via flat coalesced bursts, then
// wave w computes image row ry+w from LDS. Stores happen per 64-px chunk
// (16-lane group) only where that chunk holds a nonzero.
__global__ __launch_bounds__(512, 8) void conv0_kernel(
    const float* __restrict__ pred, const float* __restrict__ tgt,
    float* __restrict__ out, unsigned short* __restrict__ Fout,
    unsigned* __restrict__ cntOut, unsigned* __restrict__ omin,
    unsigned* __restrict__ omax, double* __restrict__ osum) {
    int blk = blockIdx.x;
    blk = (blk & 7) * (NB0 >> 3) + (blk >> 3);  // XCD swizzle (4096%8==0)
    const int s = blk >> 7, ty = blk & 127, ry = ty << 3;
    const int tid = threadIdx.x, lane = tid & 63, w = tid >> 6;  // w: 0..7
    const size_t sbase = (size_t)s * NPIX;

    __shared__ float sb[10 * 1024];  // 40 KB

    // ---- stage: 10 rows x 1024 px = 2560 float4 slots, 5 per thread ----
    float4 pv[5], tv[5];
#pragma unroll
    for (int i = 0; i < 5; ++i) {
        const int slot = tid + 512 * i;
        const int y = ry - 1 + (slot >> 8);
        if (y >= 0 && y < HH) {
            const size_t idx = sbase + (size_t)y * WW + ((slot & 255) << 2);
            pv[i] = ld4f(pred + idx);
            tv[i] = ld4f(tgt + idx);
        } else {
            pv[i] = make_float4(0.f, 0.f, 0.f, 0.f);
            tv[i] = make_float4(0.f, 0.f, 0.f, 0.f);
        }
    }
#pragma unroll
    for (int i = 0; i < 5; ++i) {
        const int slot = tid + 512 * i;
        float4 b;
        b.x = (pv[i].x - tv[i].x) * (pv[i].x - tv[i].x);
        b.y = (pv[i].y - tv[i].y) * (pv[i].y - tv[i].y);
        b.z = (pv[i].z - tv[i].z) * (pv[i].z - tv[i].z);
        b.w = (pv[i].w - tv[i].w) * (pv[i].w - tv[i].w);
        *reinterpret_cast<float4*>(
            &sb[(slot >> 8) * 1024 + ((slot & 255) << 2)]) = b;
    }
    __syncthreads();

    // ---- compute: wave w handles image row y = ry+w ----
    float lmin = 3.4e38f, lmax = 0.f, lsum = 0.f;
    unsigned rowmask = 0u;
    const int y = ry + w;
#pragma unroll
    for (int q = 0; q < 4; ++q) {
        const int xw = (q << 8) + (lane << 2);
        const float4 U = *(const float4*)&sb[w * 1024 + xw];
        const float4 Cc = *(const float4*)&sb[(w + 1) * 1024 + xw];
        const float4 D = *(const float4*)&sb[(w + 2) * 1024 + xw];
        float lf = __shfl_up(Cc.w, 1);
        if (lane == 0) lf = (q > 0) ? sb[(w + 1) * 1024 + (q << 8) - 1] : 0.f;
        float rt = __shfl_down(Cc.x, 1);
        if (lane == 63)
            rt = (q < 3) ? sb[(w + 1) * 1024 + (q << 8) + 256] : 0.f;
        const float cv[4] = {Cc.x, Cc.y, Cc.z, Cc.w};
        const float uv[4] = {U.x, U.y, U.z, U.w};
        const float dv[4] = {D.x, D.y, D.z, D.w};
        const float lvv[4] = {lf, Cc.x, Cc.y, Cc.z};
        const float rvv[4] = {Cc.y, Cc.z, Cc.w, rt};
        float O[4];
        bool nz = false;
#pragma unroll
        for (int j = 0; j < 4; ++j) {
            const float conv = 0.2f * (uv[j] + dv[j] + cv[j] + lvv[j] + rvv[j]);
            const float er = fmaxf(conv - 0.5f, 0.f);
            O[j] = er;
            lmin = fminf(lmin, er);
            lmax = fmaxf(lmax, er);
            lsum += er;
            nz = nz || (er > 0.f);
        }
        const unsigned long long bal = __ballot(nz);
        // chunk = 16 lanes = 64 px; store only chunks containing a nonzero
        const bool myChunk =
            ((bal >> ((lane >> 4) << 4)) & 0xFFFFull) != 0ull;
        if (myChunk)
            *reinterpret_cast<float4*>(out + sbase + (size_t)y * WW + xw) =
                make_float4(O[0], O[1], O[2], O[3]);
        unsigned g = 0;
        if ((bal)&0xFFFFull) g |= 1u;
        if ((bal >> 16) & 0xFFFFull) g |= 2u;
        if ((bal >> 32) & 0xFFFFull) g |= 4u;
        if ((bal >> 48) & 0xFFFFull) g |= 8u;
        rowmask |= g << (q << 2);
    }
    if (lane == 0) Fout[s * FRPS + y] = (unsigned short)rowmask;  // owned row

    // ---- block reduce (8 waves) ----
#pragma unroll
    for (int off = 32; off > 0; off >>= 1) {
        lmin = fminf(lmin, __shfl_down(lmin, off));
        lmax = fmaxf(lmax, __shfl_down(lmax, off));
        lsum += __shfl_down(lsum, off);
    }
    __shared__ float smn[8], smx[8], ssm[8];
    __shared__ unsigned sfb[8];
    if (lane == 0) {
        smn[w] = lmin;
        smx[w] = lmax;
        ssm[w] = lsum;
        sfb[w] = rowmask;
    }
    __syncthreads();
    if (tid == 0) {
        unsigned any = sfb[0];
        float bmn = smn[0], bmx = smx[0], bsm = ssm[0];
#pragma unroll
        for (int i = 1; i < 8; ++i) {
            bmn = fminf(bmn, smn[i]);
            bmx = fmaxf(bmx, smx[i]);
            bsm += ssm[i];
            any |= sfb[i];
        }
        if (any) atomicAdd(cntOut, 1u);
        atomicMin(&omin[s], __float_as_uint(bmn));
        if (bmx > 0.f) atomicMax(&omax[s], __float_as_uint(bmx));
        if (bsm > 0.f) atomicAdd(&osum[s], (double)bsm);
    }
}

// ---------------- iterations 1..9 (chunk-sparse tail) ----------------
// Block = 16-row tile, 4 waves; wave w owns rows [ry+4w, ry+4w+4); lane owns
// 16 px (= quarter of a 64-px chunk; chunk = 4 lanes). Loads and stores are
// gated by the per-row chunk masks. Unflagged chunks are exact zeros.
__global__ __launch_bounds__(256, 4) void convt_kernel(
    const float* __restrict__ in, float* __restrict__ out,
    const unsigned short* __restrict__ Fprev, unsigned short* __restrict__ Fout,
    const unsigned* __restrict__ cntPrev, unsigned* __restrict__ cntOut,
    const unsigned* __restrict__ pmin, const unsigned* __restrict__ pmax,
    unsigned* __restrict__ omin, unsigned* __restrict__ omax,
    double* __restrict__ osum) {
    if (*cntPrev == 0u) return;  // field died: absorbing state

    int blk = blockIdx.x;
    blk = (blk & 7) * (NTILES >> 3) + (blk >> 3);
    const int s = blk >> 6, ty = blk & 63, ry = ty << 4;
    const int tid = threadIdx.x, lane = tid & 63, w = tid >> 6;
    const int xb = lane << 4;
    const size_t sbase = (size_t)s * NPIX;

    __shared__ unsigned short sM[18];  // masks of rows ry-1 .. ry+16
    __shared__ int sSkip;
    if (tid < 18) {
        const int yy = ry - 1 + tid;
        sM[tid] =
            (yy >= 0 && yy < HH) ? Fprev[s * FRPS + yy] : (unsigned short)0;
    }
    __syncthreads();
    if (tid == 0) {
        unsigned any = 0;
#pragma unroll
        for (int i = 0; i < 18; ++i) any |= sM[i];
        sSkip = (any == 0u);
    }
    __syncthreads();
    if (sSkip) {  // nothing in reach: tile output exactly zero
        if (tid == 0) atomicMin(&omin[s], 0u);
        return;
    }

    float a = 1.f, cc = 0.f;
    {
        const float mn = __uint_as_float(pmin[s]);
        const float mx = __uint_as_float(pmax[s]);
        const float ptp = mx - mn;
        if (ptp > 0.f) { a = 1.f / ptp; cc = mn; }
    }

    const int r0 = w << 2;
    float A[16], B[16], C[16], O[16];

    // load row y (mask-gated per chunk; sM==0 rows -> zeros, incl. borders)
    auto loadRow = [&](int y, float* V) {
        const unsigned mask = sM[y - ry + 1];
        if (!((mask >> (lane >> 2)) & 1u)) {
#pragma unroll
            for (int j = 0; j < 16; ++j) V[j] = 0.f;
            return;
        }
        const size_t idx = sbase + (size_t)y * WW + xb;
#pragma unroll
        for (int q = 0; q < 4; ++q) {
            const float4 v = ld4f(in + idx + 4 * q);
            V[4 * q + 0] = v.x;
            V[4 * q + 1] = v.y;
            V[4 * q + 2] = v.z;
            V[4 * q + 3] = v.w;
        }
    };

    loadRow(ry + r0 - 1, A);
    loadRow(ry + r0, B);

    float lmin = 3.4e38f, lmax = 0.f, lsum = 0.f;
    unsigned blockAny = 0u;

#pragma unroll
    for (int r = 0; r < 4; ++r) {
        const int y = ry + r0 + r;
        loadRow(y + 1, C);
        const int mi = r0 + r + 1;  // sM index of row y
        const bool act = (sM[mi - 1] | sM[mi] | sM[mi + 1]) != 0;
        if (act) {
            float lfe = __shfl_up(B[15], 1);
            if (lane == 0) lfe = 0.f;
            float rte = __shfl_down(B[0], 1);
            if (lane == 63) rte = 0.f;
            const float vert =
                1.f + (y > 0 ? 1.f : 0.f) + (y < HH - 1 ? 1.f : 0.f);
            bool nz = false;
#pragma unroll
            for (int j = 0; j < 16; ++j) {
                const float lf = (j == 0) ? lfe : B[j - 1];
                const float rt = (j == 15) ? rte : B[j + 1];
                const float conv = 0.2f * (A[j] + C[j] + B[j] + lf + rt);
                const int x = xb + j;
                const float kf = 0.2f * (vert + (x > 0 ? 1.f : 0.f) +
                                         (x < WW - 1 ? 1.f : 0.f));
                const float dil = (conv - cc * kf) * a;
                const float er = fmaxf(dil - 0.5f, 0.f);
                O[j] = er;
                lmin = fminf(lmin, er);
                lmax = fmaxf(lmax, er);
                lsum += er;
                nz = nz || (er > 0.f);
            }
            const unsigned long long bal = __ballot(nz);
            // chunk = 4 lanes = 64 px; store lane's 16 px iff chunk nonzero
            if (((bal >> ((lane >> 2) << 2)) & 0xFull) != 0ull) {
                const size_t oidx = sbase + (size_t)y * WW + xb;
#pragma unroll
                for (int q = 0; q < 4; ++q)
                    *reinterpret_cast<float4*>(out + oidx + 4 * q) =
                        make_float4(O[4 * q], O[4 * q + 1], O[4 * q + 2],
                                    O[4 * q + 3]);
            }
            unsigned rm = 0;
#pragma unroll
            for (int c = 0; c < 16; ++c)
                if ((bal >> (c << 2)) & 0xFull) rm |= 1u << c;
            if (lane == 0) Fout[s * FRPS + y] = (unsigned short)rm;  // owned
            blockAny |= rm;
        } else {
            lmin = fminf(lmin, 0.f);  // row is exactly zero (mask pre-zeroed)
        }
#pragma unroll
        for (int j = 0; j < 16; ++j) {
            A[j] = B[j];
            B[j] = C[j];
        }
    }

#pragma unroll
    for (int off = 32; off > 0; off >>= 1) {
        lmin = fminf(lmin, __shfl_down(lmin, off));
        lmax = fmaxf(lmax, __shfl_down(lmax, off));
        lsum += __shfl_down(lsum, off);
    }
    __shared__ float smn[4], smx[4], ssm[4];
    __shared__ unsigned sfb[4];
    if (lane == 0) {
        smn[w] = lmin;
        smx[w] = lmax;
        ssm[w] = lsum;
        sfb[w] = blockAny;
    }
    __syncthreads();
    if (tid == 0) {
        const unsigned any = sfb[0] | sfb[1] | sfb[2] | sfb[3];
        float bmn = smn[0], bmx = smx[0], bsm = ssm[0];
#pragma unroll
        for (int i = 1; i < 4; ++i) {
            bmn = fminf(bmn, smn[i]);
            bmx = fmaxf(bmx, smx[i]);
            bsm += ssm[i];
        }
        if (any) atomicAdd(cntOut, 1u);
        atomicMin(&omin[s], __float_as_uint(bmn));
        if (bmx > 0.f) atomicMax(&omax[s], __float_as_uint(bmx));
        if (bsm > 0.f) atomicAdd(&osum[s], (double)bsm);
    }
}

__global__ void init_kernel(unsigned* __restrict__ minb,
                            unsigned* __restrict__ maxb,
                            double* __restrict__ sums,
                            unsigned* __restrict__ F16u,
                            unsigned* __restrict__ cnt) {
    const int i = blockIdx.x * blockDim.x + threadIdx.x;
    if (i < NEROS * BATCH) {
        minb[i] = 0x7f800000u;  // +inf
        maxb[i] = 0u;
        sums[i] = 0.0;
    }
    if (i < NEROS * BATCH * FRPS / 2) F16u[i] = 0u;  // ushort masks, as uints
    if (i < NEROS) cnt[i] = 0u;
}

__global__ void final_kernel(const unsigned* __restrict__ minb,
                             const unsigned* __restrict__ maxb,
                             const double* __restrict__ sums,
                             float* __restrict__ out) {
    const int s = threadIdx.x;
    double tot = 0.0;
    if (s < BATCH) {
        for (int k = 0; k < NEROS; ++k) {
            const float mn = __uint_as_float(minb[k * BATCH + s]);
            const float mx = __uint_as_float(maxb[k * BATCH + s]);
            const double sm = sums[k * BATCH + s];
            const float ptp = mx - mn;
            double v;
            if (ptp > 0.f)
                v = (sm - (double)NPIX * (double)mn) / (double)ptp;
            else
                v = sm;
            tot += (double)((k + 1) * (k + 1)) * v;
        }
    }
#pragma unroll
    for (int off = 32; off > 0; off >>= 1) tot += __shfl_down(tot, off);
    if (s == 0) out[0] = (float)(tot / ((double)BATCH * (double)NPIX));
}

extern "C" void kernel_launch(void* const* d_in, const int* in_sizes, int n_in,
                              void* d_out, int out_size, void* d_ws,
                              size_t ws_size, hipStream_t stream) {
    const float* pred = (const float*)d_in[0];
    const float* tgt = (const float*)d_in[1];
    float* out = (float*)d_out;

    float* buf0 = (float*)d_ws;
    float* buf1 = buf0 + (size_t)BATCH * NPIX;
    unsigned* minb = (unsigned*)(buf1 + (size_t)BATCH * NPIX);
    unsigned* maxb = minb + NEROS * BATCH;
    double* sums = (double*)(maxb + NEROS * BATCH);
    unsigned short* F = (unsigned short*)(sums + NEROS * BATCH);
    unsigned* cnt = (unsigned*)(F + (size_t)NEROS * BATCH * FRPS);

    init_kernel<<<640, 256, 0, stream>>>(minb, maxb, sums, (unsigned*)F, cnt);

    conv0_kernel<<<NB0, 512, 0, stream>>>(pred, tgt, buf0, F, &cnt[0], minb,
                                          maxb, sums);

    float* bufs[2] = {buf0, buf1};
    for (int k = 1; k < NEROS; ++k) {
        const float* src = bufs[(k - 1) & 1];
        float* dst = bufs[k & 1];
        convt_kernel<<<NTILES, 256, 0, stream>>>(
            src, dst, F + (size_t)(k - 1) * BATCH * FRPS,
            F + (size_t)k * BATCH * FRPS, &cnt[k - 1], &cnt[k],
            minb + (size_t)(k - 1) * BATCH, maxb + (size_t)(k - 1) * BATCH,
            minb + (size_t)k * BATCH, maxb + (size_t)k * BATCH,
            sums + (size_t)k * BATCH);
    }

    final_kernel<<<1, 64, 0, stream>>>(minb, maxb, sums, out);
}